// Round 1
// baseline (413.822 us; speedup 1.0000x reference)
//
#include <hip/hip_runtime.h>
#include <hip/hip_bf16.h>

// InflateHexToVertex: out[b,n,v] = sum_{j<3,d<128} hex[b, idx[n,j], d] * W[j*128+d, v] + bias[v]
// GEMM view: M=B*N=640000 (gathered rows), K=384, N=V=128. bf16 MFMA, fp32 accum.

typedef __attribute__((ext_vector_type(8))) short short8;   // 8 bf16 = 4 VGPRs
typedef __attribute__((ext_vector_type(4))) float f32x4;    // MFMA accumulator

#define BATCH 32
#define TILES 512
#define DDIM 128
#define NVERT 20000
#define VDIM 128
#define KDIM 384            // 3*DDIM
#define ROWS_PER_BLK 32
#define LDA 392             // 384 + 8 pad (row stride 784B -> balanced LDS banks)

__device__ __forceinline__ short f2bf(float x) {
    union { float f; unsigned u; } c; c.f = x;
    unsigned r = c.u + 0x7fffu + ((c.u >> 16) & 1u);   // RNE
    return (short)(r >> 16);
}

// Pre-pack W (384x128 f32, row-major) into bf16 MFMA B-fragments.
// Fragment layout for mfma_f32_16x16x32_bf16 B-operand:
//   lane l holds B[k = 32*ks + 8*(l>>4) + j][v = 16*ct + (l&15)], j=0..7 contiguous.
// Storage: Wf[((ks*8 + ct)*64 + l)*8 + j]  -> 16B per lane, coalesced loads.
__global__ void wconv_kernel(const float* __restrict__ W, short* __restrict__ Wf) {
    int id = blockIdx.x * 256 + threadIdx.x;
    if (id >= 12 * 8 * 64 * 8) return;
    int j  = id & 7;
    int l  = (id >> 3) & 63;
    int ct = (id >> 9) & 7;
    int ks = id >> 12;
    int k = ks * 32 + (l >> 4) * 8 + j;
    int v = ct * 16 + (l & 15);
    Wf[id] = f2bf(W[k * VDIM + v]);
}

__global__ __launch_bounds__(256)
void inflate_kernel(const float* __restrict__ hex,
                    const int* __restrict__ vidx,
                    const short8* __restrict__ Wf,
                    const float* __restrict__ bias,
                    float* __restrict__ out) {
    __shared__ short A_lds[ROWS_PER_BLK * LDA];

    const int tid = threadIdx.x;
    const int bb  = blockIdx.y;
    const int n0  = blockIdx.x * ROWS_PER_BLK;
    const float* hexb = hex + (size_t)bb * (TILES * DDIM);

    // ---- Stage gathered A-tile (32 rows x 384) as bf16 into LDS ----
    // 1536 chunks of 8 elems; chunk c: row r, hex-slot j, d-offset d0.
    for (int c = tid; c < ROWS_PER_BLK * 48; c += 256) {
        int rj = c >> 4;                 // (r,j) pair index, 16 chunks each
        int d0 = (c & 15) << 3;          // 0..120
        int r  = rj / 3;
        int j  = rj - r * 3;
        int hx = vidx[(n0 + r) * 3 + j];
        short8 v8 = {0, 0, 0, 0, 0, 0, 0, 0};
        if (hx >= 0) {
            const f32x4* src = (const f32x4*)(hexb + hx * DDIM + d0);
            f32x4 f0 = src[0];
            f32x4 f1 = src[1];
            v8[0] = f2bf(f0[0]); v8[1] = f2bf(f0[1]);
            v8[2] = f2bf(f0[2]); v8[3] = f2bf(f0[3]);
            v8[4] = f2bf(f1[0]); v8[5] = f2bf(f1[1]);
            v8[6] = f2bf(f1[2]); v8[7] = f2bf(f1[3]);
        }
        *(short8*)&A_lds[r * LDA + (j << 7) + d0] = v8;
    }
    __syncthreads();

    // ---- MFMA main loop: wave w -> cols [32w, 32w+32), rows [0,32) ----
    const int lane = tid & 63;
    const int w    = tid >> 6;
    const int lw   = lane & 15;
    const int lh   = lane >> 4;

    f32x4 acc[2][2];
    #pragma unroll
    for (int a = 0; a < 2; ++a)
        #pragma unroll
        for (int b2 = 0; b2 < 2; ++b2) {
            f32x4 z = {0.f, 0.f, 0.f, 0.f};
            acc[a][b2] = z;
        }

    // A-fragment: lane l reads A[row = rt*16 + lw][k = ks*32 + lh*8 .. +7]
    const short* a0p = &A_lds[lw * LDA + lh * 8];
    const short* a1p = a0p + 16 * LDA;

    #pragma unroll
    for (int ks = 0; ks < 12; ++ks) {
        short8 a0 = *(const short8*)(a0p + ks * 32);
        short8 a1 = *(const short8*)(a1p + ks * 32);
        short8 b0 = Wf[(ks * 8 + 2 * w + 0) * 64 + lane];
        short8 b1 = Wf[(ks * 8 + 2 * w + 1) * 64 + lane];
        acc[0][0] = __builtin_amdgcn_mfma_f32_16x16x32_bf16(a0, b0, acc[0][0], 0, 0, 0);
        acc[0][1] = __builtin_amdgcn_mfma_f32_16x16x32_bf16(a0, b1, acc[0][1], 0, 0, 0);
        acc[1][0] = __builtin_amdgcn_mfma_f32_16x16x32_bf16(a1, b0, acc[1][0], 0, 0, 0);
        acc[1][1] = __builtin_amdgcn_mfma_f32_16x16x32_bf16(a1, b1, acc[1][1], 0, 0, 0);
    }

    // ---- Epilogue: C/D layout col=lane&15, row=(lane>>4)*4+i (verified m89/m91) ----
    const float bias0 = bias[w * 32 + lw];
    const float bias1 = bias[w * 32 + 16 + lw];
    float* outb = out + ((size_t)bb * NVERT + n0) * VDIM + w * 32;
    #pragma unroll
    for (int rt = 0; rt < 2; ++rt) {
        #pragma unroll
        for (int i = 0; i < 4; ++i) {
            int row = rt * 16 + lh * 4 + i;
            float* orow = outb + (size_t)row * VDIM;
            orow[lw]      = acc[rt][0][i] + bias0;
            orow[16 + lw] = acc[rt][1][i] + bias1;
        }
    }
}

extern "C" void kernel_launch(void* const* d_in, const int* in_sizes, int n_in,
                              void* d_out, int out_size, void* d_ws, size_t ws_size,
                              hipStream_t stream) {
    const float* hex  = (const float*)d_in[0];
    const int*   vidx = (const int*)d_in[1];     // int64 in ref -> int32 from harness
    const float* W    = (const float*)d_in[2];
    const float* bias = (const float*)d_in[3];
    float* out = (float*)d_out;
    short* Wf  = (short*)d_ws;                   // 12*8*64*8 bf16 = 96 KB

    wconv_kernel<<<192, 256, 0, stream>>>(W, Wf);

    dim3 grid(NVERT / ROWS_PER_BLK, BATCH);      // 625 x 32
    inflate_kernel<<<grid, 256, 0, stream>>>(hex, vidx, (const short8*)Wf, bias, out);
}